// Round 6
// baseline (120.483 us; speedup 1.0000x reference)
//
#include <hip/hip_runtime.h>
#include <math.h>

#define NN 32
#define CC 32
#define MM 196
#define OO 10
#define RECSZ 192       // per-(it,n,c) record: AW[0..160), S[160..170), T[170..180)
#define NEPS 1e-6f
#define NV_OFF 589824               // rec area: 3*NN*CC*RECSZ floats
#define CTR_OFF 2596864             // NV_OFF + NN*CC*OO*MM floats; 32 uint counters
#define CTR_BYTE_OFF (CTR_OFF * 4)

#define LPS 20          // lpM row stride (floats): 80B, 16B-aligned
#define RTS 208         // rT/pT row stride: 16 chunks * 13 m, rows 196..207 zero-filled

// rec(it,n,c) = ws + ((it*NN+n)*CC+c)*RECSZ
// nv(n,c)     = ws + NV_OFF + (n*CC+c)*OO*MM     layout [o][m]

__device__ __forceinline__ float rs_step(float lo, float hi, int mask, bool take_hi) {
    // reduce-scatter exchange: I keep (take_hi?hi:lo); partner sends its copy of my kept idx
    float send = take_hi ? lo : hi;
    float recv = __shfl_xor(send, mask);
    return (take_hi ? hi : lo) + recv;
}

template<int IT>   // IT=0: direct V path, gv=g, r*=0.1 ; IT=1,2: factored path; IT=2 adds T + fused finalize
__global__ __launch_bounds__(256, 4) void accum_kernel(
    const float* __restrict__ l, const float* __restrict__ g,
    const float* __restrict__ weight, const float* __restrict__ beta_a,
    float* __restrict__ out, float* __restrict__ ws)
{
    const int n = blockIdx.x >> 5, c = blockIdx.x & 31, tid = threadIdx.x;
    __shared__ float Wl[160], gvl[160], Ablk[160], Wg[160], ggs[16], Ss[16];
    __shared__ __align__(16) float lpM[RTS * LPS];   // m-major: lpM[m*LPS + ij]
    __shared__ float rT[OO * RTS];                   // rT[o*RTS + m]
    __shared__ float pT[OO * RTS];                   // IT2: r*||V||^2
    __shared__ int winner;

    if (tid < 160) Wl[tid] = weight[c * 160 + tid];
    // zero-fill pad rows m=196..207 so chunk 15 contributes zeros
    if (tid < 192) lpM[(196 + (tid >> 4)) * LPS + (tid & 15)] = 0.f;
    if (tid < 120) {
        rT[(tid / 12) * RTS + 196 + (tid % 12)] = 0.f;
        if (IT == 2) pT[(tid / 12) * RTS + 196 + (tid % 12)] = 0.f;
    }

    if constexpr (IT == 0) {
        if (tid < 160) gvl[tid] = g[n * 160 + tid];
    } else {
        // inline reduce of previous iteration's records for this n (L2-hot)
        const float* base = ws + ((size_t)((IT - 1) * NN + n) * CC) * RECSZ;
        if (tid < 160) {
            float u = 0.f;
            for (int cc2 = 0; cc2 < CC; ++cc2) u += base[cc2 * RECSZ + tid];
            Ablk[tid] = u;                                  // UV (temp)
        } else if (tid < 170) {
            float s = 0.f;
            for (int cc2 = 0; cc2 < CC; ++cc2) s += base[cc2 * RECSZ + 160 + (tid - 160)];
            Ss[tid - 160] = s + NEPS;
        }
        __syncthreads();
        if (tid < 160) gvl[tid] = Ablk[tid] / Ss[tid >> 4]; // gv = UV/(S+EPS)
        __syncthreads();
        if (tid < 160) {                                    // Wg[o,i,j] = sum_k W[o,j,k]*gv[o,i,k]
            const int o = tid >> 4, i = (tid >> 2) & 3, j = tid & 3;
            float acc = 0.f;
            #pragma unroll
            for (int k = 0; k < 4; ++k)
                acc = fmaf(Wl[o * 16 + j * 4 + k], gvl[o * 16 + i * 4 + k], acc);
            Wg[tid] = acc;
        } else if (tid >= 160 && tid < 170) {
            const int o = tid - 160;
            float s = 0.f;
            #pragma unroll
            for (int e = 0; e < 16; ++e) s = fmaf(gvl[o * 16 + e], gvl[o * 16 + e], s);
            ggs[o] = s;                                     // ||gv_o||^2
        }
    }

    const bool act = tid < MM;
    float lp[16];
    if (act) {
        const float* lbase = l + ((size_t)(n * CC + c)) * (16 * MM) + tid;
        #pragma unroll
        for (int dd = 0; dd < 16; ++dd) lp[dd] = lbase[dd * MM];   // coalesced
        float4* dst = (float4*)&lpM[tid * LPS];
        dst[0] = make_float4(lp[0],  lp[1],  lp[2],  lp[3]);
        dst[1] = make_float4(lp[4],  lp[5],  lp[6],  lp[7]);
        dst[2] = make_float4(lp[8],  lp[9],  lp[10], lp[11]);
        dst[3] = make_float4(lp[12], lp[13], lp[14], lp[15]);
    }
    __syncthreads();   // gvl/Wg/ggs/lpM(+pads) ready

    float* nvg = ws + NV_OFF + (size_t)(n * CC + c) * (OO * MM);
    if (act) {
        const int m = tid;
        float rn[OO], nvl[OO];
        float rd = 0.f;
        #pragma unroll
        for (int o = 0; o < OO; ++o) {
            float dist;
            if constexpr (IT == 0) {
                float nvv = 0.f; dist = 0.f;
                #pragma unroll
                for (int i = 0; i < 4; ++i) {
                    #pragma unroll
                    for (int k = 0; k < 4; ++k) {
                        float v = 0.f;
                        #pragma unroll
                        for (int j = 0; j < 4; ++j)
                            v = fmaf(lp[i * 4 + j], Wl[o * 16 + j * 4 + k], v);
                        nvv = fmaf(v, v, nvv);
                        float dv = v - gvl[o * 16 + i * 4 + k];
                        dist = fmaf(dv, dv, dist);
                    }
                }
                nvg[o * MM + m] = nvv;      // persist ||V||^2 for iters 1-2
            } else {
                const float nvv = nvg[o * MM + m];   // coalesced reload
                nvl[o] = nvv;
                const float4* wg4 = (const float4*)&Wg[o * 16];
                float4 w0 = wg4[0], w1 = wg4[1], w2 = wg4[2], w3 = wg4[3];
                float dot = 0.f;
                dot = fmaf(lp[0],  w0.x, dot); dot = fmaf(lp[1],  w0.y, dot);
                dot = fmaf(lp[2],  w0.z, dot); dot = fmaf(lp[3],  w0.w, dot);
                dot = fmaf(lp[4],  w1.x, dot); dot = fmaf(lp[5],  w1.y, dot);
                dot = fmaf(lp[6],  w1.z, dot); dot = fmaf(lp[7],  w1.w, dot);
                dot = fmaf(lp[8],  w2.x, dot); dot = fmaf(lp[9],  w2.y, dot);
                dot = fmaf(lp[10], w2.z, dot); dot = fmaf(lp[11], w2.w, dot);
                dot = fmaf(lp[12], w3.x, dot); dot = fmaf(lp[13], w3.y, dot);
                dot = fmaf(lp[14], w3.z, dot); dot = fmaf(lp[15], w3.w, dot);
                dist = fmaxf(nvv - 2.f * dot + ggs[o], 0.f);   // ||V-gv||^2, guarded
            }
            rn[o] = dist + NEPS;
            rd += 1.0f / rn[o];
        }
        #pragma unroll
        for (int o = 0; o < OO; ++o) {
            float t = 1.0f / (rn[o] * rd);
            float r = t * t;
            if constexpr (IT == 0) r *= 0.1f;      // a_in / N_CLASSES
            rT[o * RTS + m] = r;
            if constexpr (IT == 2) pT[o * RTS + m] = r * nvl[o];
        }
    }
    __syncthreads();   // rT (and pT) ready

    float* rec = ws + ((size_t)(IT * NN + n) * CC + c) * RECSZ;
    // ---- chunked reduction: thread (o, chunk) handles 13 m's x all 16 ij ----
    if (tid < 160) {
        const int o = tid >> 4, ch = tid & 15;
        const int m0 = ch * 13;
        float a0=0,a1=0,a2=0,a3=0,a4=0,a5=0,a6=0,a7=0;
        float a8=0,a9=0,a10=0,a11=0,a12=0,a13=0,a14=0,a15=0;
        float sacc = 0.f, tacc = 0.f;
        #pragma unroll
        for (int i = 0; i < 13; ++i) {
            const int m = m0 + i;
            const float r = rT[o * RTS + m];
            const float4* lq = (const float4*)&lpM[m * LPS];
            float4 l0 = lq[0], l1 = lq[1], l2 = lq[2], l3 = lq[3];
            a0  = fmaf(r, l0.x, a0);  a1  = fmaf(r, l0.y, a1);
            a2  = fmaf(r, l0.z, a2);  a3  = fmaf(r, l0.w, a3);
            a4  = fmaf(r, l1.x, a4);  a5  = fmaf(r, l1.y, a5);
            a6  = fmaf(r, l1.z, a6);  a7  = fmaf(r, l1.w, a7);
            a8  = fmaf(r, l2.x, a8);  a9  = fmaf(r, l2.y, a9);
            a10 = fmaf(r, l2.z, a10); a11 = fmaf(r, l2.w, a11);
            a12 = fmaf(r, l3.x, a12); a13 = fmaf(r, l3.y, a13);
            a14 = fmaf(r, l3.z, a14); a15 = fmaf(r, l3.w, a15);
            sacc += r;
            if constexpr (IT == 2) tacc += pT[o * RTS + m];
        }
        // ---- 16-lane reduce-scatter: lane (o,p) ends holding A[o][p] ----
        const int p = tid & 15;
        const bool h1 = (p & 1), h2 = (p & 2), h4 = (p & 4), h8 = (p & 8);
        float b0 = rs_step(a0,  a1,  1, h1), b1 = rs_step(a2,  a3,  1, h1);
        float b2 = rs_step(a4,  a5,  1, h1), b3 = rs_step(a6,  a7,  1, h1);
        float b4 = rs_step(a8,  a9,  1, h1), b5 = rs_step(a10, a11, 1, h1);
        float b6 = rs_step(a12, a13, 1, h1), b7 = rs_step(a14, a15, 1, h1);
        float c0 = rs_step(b0, b1, 2, h2), c1 = rs_step(b2, b3, 2, h2);
        float c2 = rs_step(b4, b5, 2, h2), c3 = rs_step(b6, b7, 2, h2);
        float d0 = rs_step(c0, c1, 4, h4), d1 = rs_step(c2, c3, 4, h4);
        float e  = rs_step(d0, d1, 8, h8);
        #pragma unroll
        for (int mk = 1; mk <= 8; mk <<= 1) {
            sacc += __shfl_xor(sacc, mk);
            if constexpr (IT == 2) tacc += __shfl_xor(tacc, mk);
        }
        Ablk[tid] = e;
        if (p == 0) rec[160 + o] = sacc;
        if (IT == 2 && p == 1) rec[170 + o] = tacc;
    }
    __syncthreads();   // Ablk ready
    if (tid < 160) {   // AW = A @ W[c,o]
        const int o = tid >> 4, ik = tid & 15, i = ik >> 2, k = ik & 3;
        float aw = 0.f;
        #pragma unroll
        for (int j = 0; j < 4; ++j)
            aw = fmaf(Ablk[o * 16 + i * 4 + j], Wl[o * 16 + j * 4 + k], aw);
        rec[tid] = aw;
    }

    // ---- IT==2: last-arriving block per n runs finalize inline (deadlock-free) ----
    if constexpr (IT == 2) {
        __syncthreads();           // all rec writes issued
        __threadfence();           // release: recs visible device-wide
        if (tid == 0) {
            unsigned int* ctr = (unsigned int*)(ws + CTR_OFF);
            unsigned int old = atomicAdd(&ctr[n], 1u);
            winner = (old == CC - 1) ? 1 : 0;
        }
        __syncthreads();
        if (!winner) return;
        __threadfence();           // acquire: see all other blocks' recs

        const float* base = ws + ((size_t)(2 * NN + n) * CC) * RECSZ;
        float uacc = 0.f;
        if (tid < 160) {
            for (int cc2 = 0; cc2 < CC; ++cc2) uacc += base[cc2 * RECSZ + tid];
        } else if (tid < 170) {
            const int o = tid - 160;
            float s = 0.f, t = 0.f;
            for (int cc2 = 0; cc2 < CC; ++cc2) {
                s += base[cc2 * RECSZ + 160 + o];
                t += base[cc2 * RECSZ + 170 + o];
            }
            Ss[o] = s + NEPS;
            ggs[o] = t;            // reuse ggs as Tred
        }
        __syncthreads();
        if (tid < 160) {
            const float gvv = uacc / Ss[tid >> 4];
            out[NN * OO + (size_t)n * 160 + tid] = gvv;
            gvl[tid] = gvv;
        }
        __syncthreads();
        if (tid < OO) {
            float g2 = 0.f;
            #pragma unroll
            for (int e2 = 0; e2 < 16; ++e2)
                g2 = fmaf(gvl[tid * 16 + e2], gvl[tid * 16 + e2], g2);
            const float S1 = Ss[tid];
            // sigma = T/(S+EPS) - ||gv||^2*(S+2EPS)/(S+EPS)   (exact coeff-fold algebra)
            float sigma = ggs[tid] / S1 - g2 * (S1 + NEPS) / S1;
            sigma = fmaxf(sigma, 1e-30f);
            const float x = 0.01f * (beta_a[tid] - 0.5f * logf(sigma));
            out[n * OO + tid] = 1.0f / (1.0f + expf(-x));
        }
    }
}

extern "C" void kernel_launch(void* const* d_in, const int* in_sizes, int n_in,
                              void* d_out, int out_size, void* d_ws, size_t ws_size,
                              hipStream_t stream)
{
    const float* l      = (const float*)d_in[0];
    const float* g      = (const float*)d_in[1];
    const float* weight = (const float*)d_in[2];
    const float* beta_a = (const float*)d_in[3];
    float* out = (float*)d_out;
    float* ws  = (float*)d_ws;

    // zero the arrival counters (graph-capturable memset node)
    hipMemsetAsync((char*)d_ws + CTR_BYTE_OFF, 0, NN * sizeof(unsigned int), stream);

    dim3 gA(NN * CC), bA(256);
    accum_kernel<0><<<gA, bA, 0, stream>>>(l, g, weight, beta_a, out, ws);
    accum_kernel<1><<<gA, bA, 0, stream>>>(l, g, weight, beta_a, out, ws);
    accum_kernel<2><<<gA, bA, 0, stream>>>(l, g, weight, beta_a, out, ws);
}

// Round 7
// 39.385 us; speedup vs baseline: 3.0591x; 3.0591x over previous
//
#include <hip/hip_runtime.h>
#include <math.h>

#define NN 32
#define CC 32
#define MM 196
#define OO 10
#define RECSZ 192       // per-(it,n,c) record: AW[0..160), S[160..170), T[170..180)
#define NEPS 1e-6f
#define NV_OFF 589824   // rec area: 3*NN*CC*RECSZ floats; nv area: NN*CC*OO*MM floats

#define LPS 20          // lpM row stride (floats): 80B, 16B-aligned
#define RTS 208         // rT/pT row stride: 16 chunks * 13 m, rows 196..207 zero-filled

// rec(it,n,c) = ws + ((it*NN+n)*CC+c)*RECSZ
// nv(n,c)     = ws + NV_OFF + (n*CC+c)*OO*MM     layout [o][m]

__device__ __forceinline__ float rs_step(float lo, float hi, int mask, bool take_hi) {
    // reduce-scatter exchange: I keep (take_hi?hi:lo); partner sends its copy of my kept idx
    float send = take_hi ? lo : hi;
    float recv = __shfl_xor(send, mask);
    return (take_hi ? hi : lo) + recv;
}

template<int IT>   // IT=0: direct V path, gv=g, r*=0.1 ; IT=1,2: factored path; IT=2 adds T
__global__ __launch_bounds__(256, 4) void accum_kernel(
    const float* __restrict__ l, const float* __restrict__ g,
    const float* __restrict__ weight, float* __restrict__ ws)
{
    const int n = blockIdx.x >> 5, c = blockIdx.x & 31, tid = threadIdx.x;
    __shared__ __align__(16) float Wl[160], gvl[160], Wg[160];
    __shared__ float Ablk[160], ggs[16], Ss[16];
    __shared__ __align__(16) float lpM[RTS * LPS];   // m-major: lpM[m*LPS + ij]
    __shared__ float rT[OO * RTS];                   // rT[o*RTS + m]
    __shared__ float pT[OO * RTS];                   // IT2: r*||V||^2 (LDS)

    if (tid < 160) Wl[tid] = weight[c * 160 + tid];
    // zero-fill pad rows m=196..207 so chunk 15 contributes zeros
    if (tid < 192) lpM[(196 + (tid >> 4)) * LPS + (tid & 15)] = 0.f;
    if (tid < 120) {
        rT[(tid / 12) * RTS + 196 + (tid % 12)] = 0.f;
        if (IT == 2) pT[(tid / 12) * RTS + 196 + (tid % 12)] = 0.f;
    }

    if constexpr (IT == 0) {
        if (tid < 160) gvl[tid] = g[n * 160 + tid];
    } else {
        // inline reduce of previous iteration's records for this n (L2-hot)
        const float* base = ws + ((size_t)((IT - 1) * NN + n) * CC) * RECSZ;
        if (tid < 160) {
            float u = 0.f;
            for (int cc2 = 0; cc2 < CC; ++cc2) u += base[cc2 * RECSZ + tid];
            Ablk[tid] = u;                                  // UV (temp)
        } else if (tid < 170) {
            float s = 0.f;
            for (int cc2 = 0; cc2 < CC; ++cc2) s += base[cc2 * RECSZ + 160 + (tid - 160)];
            Ss[tid - 160] = s + NEPS;
        }
        __syncthreads();
        if (tid < 160) gvl[tid] = Ablk[tid] / Ss[tid >> 4]; // gv = UV/(S+EPS)
        __syncthreads();
        if (tid < 160) {                                    // Wg[o,i,j] = sum_k W[o,j,k]*gv[o,i,k]
            const int o = tid >> 4, i = (tid >> 2) & 3, j = tid & 3;
            float acc = 0.f;
            #pragma unroll
            for (int k = 0; k < 4; ++k)
                acc = fmaf(Wl[o * 16 + j * 4 + k], gvl[o * 16 + i * 4 + k], acc);
            Wg[tid] = acc;
        } else if (tid >= 160 && tid < 170) {
            const int o = tid - 160;
            float s = 0.f;
            #pragma unroll
            for (int e = 0; e < 16; ++e) s = fmaf(gvl[o * 16 + e], gvl[o * 16 + e], s);
            ggs[o] = s;                                     // ||gv_o||^2
        }
    }

    const bool act = tid < MM;
    float lp[16];
    if (act) {
        const float* lbase = l + ((size_t)(n * CC + c)) * (16 * MM) + tid;
        #pragma unroll
        for (int dd = 0; dd < 16; ++dd) lp[dd] = lbase[dd * MM];   // coalesced
        float4* dst = (float4*)&lpM[tid * LPS];
        dst[0] = make_float4(lp[0],  lp[1],  lp[2],  lp[3]);
        dst[1] = make_float4(lp[4],  lp[5],  lp[6],  lp[7]);
        dst[2] = make_float4(lp[8],  lp[9],  lp[10], lp[11]);
        dst[3] = make_float4(lp[12], lp[13], lp[14], lp[15]);
    }
    __syncthreads();   // gvl/Wg/ggs/lpM(+pads) ready

    float* nvg = ws + NV_OFF + (size_t)(n * CC + c) * (OO * MM);
    if (act) {
        const int m = tid;
        float rn[OO], nvl[OO];
        float rd = 0.f;
        #pragma unroll
        for (int o = 0; o < OO; ++o) {
            float dist;
            if constexpr (IT == 0) {
                // vectorized W/g tile loads: 8 x b128 LDS per o, FMAs from registers
                const float4* wrow = (const float4*)&Wl[o * 16];
                float4 w0 = wrow[0], w1 = wrow[1], w2 = wrow[2], w3 = wrow[3];  // w_j[k]
                const float4* grow = (const float4*)&gvl[o * 16];
                float4 gv0 = grow[0], gv1 = grow[1], gv2 = grow[2], gv3 = grow[3]; // g_i[k]
                float nvv = 0.f; dist = 0.f;
                #pragma unroll
                for (int i = 0; i < 4; ++i) {
                    const float li0 = lp[i * 4 + 0], li1 = lp[i * 4 + 1];
                    const float li2 = lp[i * 4 + 2], li3 = lp[i * 4 + 3];
                    float4 gi = (i == 0) ? gv0 : (i == 1) ? gv1 : (i == 2) ? gv2 : gv3;
                    float vx = li0 * w0.x; vx = fmaf(li1, w1.x, vx);
                    vx = fmaf(li2, w2.x, vx); vx = fmaf(li3, w3.x, vx);
                    float vy = li0 * w0.y; vy = fmaf(li1, w1.y, vy);
                    vy = fmaf(li2, w2.y, vy); vy = fmaf(li3, w3.y, vy);
                    float vz = li0 * w0.z; vz = fmaf(li1, w1.z, vz);
                    vz = fmaf(li2, w2.z, vz); vz = fmaf(li3, w3.z, vz);
                    float vw = li0 * w0.w; vw = fmaf(li1, w1.w, vw);
                    vw = fmaf(li2, w2.w, vw); vw = fmaf(li3, w3.w, vw);
                    nvv = fmaf(vx, vx, nvv); nvv = fmaf(vy, vy, nvv);
                    nvv = fmaf(vz, vz, nvv); nvv = fmaf(vw, vw, nvv);
                    float dx = vx - gi.x, dy = vy - gi.y, dz = vz - gi.z, dw = vw - gi.w;
                    dist = fmaf(dx, dx, dist); dist = fmaf(dy, dy, dist);
                    dist = fmaf(dz, dz, dist); dist = fmaf(dw, dw, dist);
                }
                nvg[o * MM + m] = nvv;      // persist ||V||^2 for iters 1-2
            } else {
                const float nvv = nvg[o * MM + m];   // coalesced reload
                nvl[o] = nvv;
                const float4* wg4 = (const float4*)&Wg[o * 16];
                float4 w0 = wg4[0], w1 = wg4[1], w2 = wg4[2], w3 = wg4[3];
                float dot = 0.f;
                dot = fmaf(lp[0],  w0.x, dot); dot = fmaf(lp[1],  w0.y, dot);
                dot = fmaf(lp[2],  w0.z, dot); dot = fmaf(lp[3],  w0.w, dot);
                dot = fmaf(lp[4],  w1.x, dot); dot = fmaf(lp[5],  w1.y, dot);
                dot = fmaf(lp[6],  w1.z, dot); dot = fmaf(lp[7],  w1.w, dot);
                dot = fmaf(lp[8],  w2.x, dot); dot = fmaf(lp[9],  w2.y, dot);
                dot = fmaf(lp[10], w2.z, dot); dot = fmaf(lp[11], w2.w, dot);
                dot = fmaf(lp[12], w3.x, dot); dot = fmaf(lp[13], w3.y, dot);
                dot = fmaf(lp[14], w3.z, dot); dot = fmaf(lp[15], w3.w, dot);
                dist = fmaxf(nvv - 2.f * dot + ggs[o], 0.f);   // ||V-gv||^2, guarded
            }
            rn[o] = dist + NEPS;
            rd += 1.0f / rn[o];
        }
        #pragma unroll
        for (int o = 0; o < OO; ++o) {
            float t = 1.0f / (rn[o] * rd);
            float r = t * t;
            if constexpr (IT == 0) r *= 0.1f;      // a_in / N_CLASSES
            rT[o * RTS + m] = r;
            if constexpr (IT == 2) pT[o * RTS + m] = r * nvl[o];
        }
    }
    __syncthreads();   // rT (and pT) ready

    float* rec = ws + ((size_t)(IT * NN + n) * CC + c) * RECSZ;
    // ---- chunked reduction: thread (o, chunk) handles 13 m's x all 16 ij ----
    if (tid < 160) {
        const int o = tid >> 4, ch = tid & 15;
        const int m0 = ch * 13;
        float a0=0,a1=0,a2=0,a3=0,a4=0,a5=0,a6=0,a7=0;
        float a8=0,a9=0,a10=0,a11=0,a12=0,a13=0,a14=0,a15=0;
        float sacc = 0.f, tacc = 0.f;
        #pragma unroll
        for (int i = 0; i < 13; ++i) {
            const int m = m0 + i;
            const float r = rT[o * RTS + m];
            const float4* lq = (const float4*)&lpM[m * LPS];
            float4 l0 = lq[0], l1 = lq[1], l2 = lq[2], l3 = lq[3];
            a0  = fmaf(r, l0.x, a0);  a1  = fmaf(r, l0.y, a1);
            a2  = fmaf(r, l0.z, a2);  a3  = fmaf(r, l0.w, a3);
            a4  = fmaf(r, l1.x, a4);  a5  = fmaf(r, l1.y, a5);
            a6  = fmaf(r, l1.z, a6);  a7  = fmaf(r, l1.w, a7);
            a8  = fmaf(r, l2.x, a8);  a9  = fmaf(r, l2.y, a9);
            a10 = fmaf(r, l2.z, a10); a11 = fmaf(r, l2.w, a11);
            a12 = fmaf(r, l3.x, a12); a13 = fmaf(r, l3.y, a13);
            a14 = fmaf(r, l3.z, a14); a15 = fmaf(r, l3.w, a15);
            sacc += r;
            if constexpr (IT == 2) tacc += pT[o * RTS + m];
        }
        // ---- 16-lane reduce-scatter: lane (o,p) ends holding A[o][p] ----
        const int p = tid & 15;
        const bool h1 = (p & 1), h2 = (p & 2), h4 = (p & 4), h8 = (p & 8);
        float b0 = rs_step(a0,  a1,  1, h1), b1 = rs_step(a2,  a3,  1, h1);
        float b2 = rs_step(a4,  a5,  1, h1), b3 = rs_step(a6,  a7,  1, h1);
        float b4 = rs_step(a8,  a9,  1, h1), b5 = rs_step(a10, a11, 1, h1);
        float b6 = rs_step(a12, a13, 1, h1), b7 = rs_step(a14, a15, 1, h1);
        float c0 = rs_step(b0, b1, 2, h2), c1 = rs_step(b2, b3, 2, h2);
        float c2 = rs_step(b4, b5, 2, h2), c3 = rs_step(b6, b7, 2, h2);
        float d0 = rs_step(c0, c1, 4, h4), d1 = rs_step(c2, c3, 4, h4);
        float e  = rs_step(d0, d1, 8, h8);
        #pragma unroll
        for (int mk = 1; mk <= 8; mk <<= 1) {
            sacc += __shfl_xor(sacc, mk);
            if constexpr (IT == 2) tacc += __shfl_xor(tacc, mk);
        }
        Ablk[tid] = e;
        if (p == 0) rec[160 + o] = sacc;
        if (IT == 2 && p == 1) rec[170 + o] = tacc;
    }
    __syncthreads();   // Ablk ready
    if (tid < 160) {   // AW = A @ W[c,o]
        const int o = tid >> 4, ik = tid & 15, i = ik >> 2, k = ik & 3;
        float aw = 0.f;
        #pragma unroll
        for (int j = 0; j < 4; ++j)
            aw = fmaf(Ablk[o * 16 + i * 4 + j], Wl[o * 16 + j * 4 + k], aw);
        rec[tid] = aw;
    }
}

__global__ __launch_bounds__(256) void finalize_kernel(
    const float* __restrict__ beta_a, float* __restrict__ out, const float* __restrict__ ws)
{
    const int n = blockIdx.x, tid = threadIdx.x;
    __shared__ float Sred[OO], Tred[OO], gvl[160];

    const float* base = ws + ((size_t)(2 * NN + n) * CC) * RECSZ;
    float uacc = 0.f;
    if (tid < 160) {
        for (int cc2 = 0; cc2 < CC; ++cc2) uacc += base[cc2 * RECSZ + tid];
    } else if (tid < 170) {
        const int o = tid - 160;
        float s = 0.f, t = 0.f;
        for (int cc2 = 0; cc2 < CC; ++cc2) {
            s += base[cc2 * RECSZ + 160 + o];
            t += base[cc2 * RECSZ + 170 + o];
        }
        Sred[o] = s + NEPS;
        Tred[o] = t;
    }
    __syncthreads();
    if (tid < 160) {
        const float gvv = uacc / Sred[tid >> 4];
        out[NN * OO + (size_t)n * 160 + tid] = gvv;
        gvl[tid] = gvv;
    }
    __syncthreads();
    if (tid < OO) {
        float g2 = 0.f;
        #pragma unroll
        for (int e = 0; e < 16; ++e) g2 = fmaf(gvl[tid * 16 + e], gvl[tid * 16 + e], g2);
        const float S1 = Sred[tid];
        // sigma = T/(S+EPS) - ||gv||^2*(S+2EPS)/(S+EPS)   (exact coeff-fold algebra)
        float sigma = Tred[tid] / S1 - g2 * (S1 + NEPS) / S1;
        sigma = fmaxf(sigma, 1e-30f);
        const float x = 0.01f * (beta_a[tid] - 0.5f * logf(sigma));
        out[n * OO + tid] = 1.0f / (1.0f + expf(-x));
    }
}

extern "C" void kernel_launch(void* const* d_in, const int* in_sizes, int n_in,
                              void* d_out, int out_size, void* d_ws, size_t ws_size,
                              hipStream_t stream)
{
    const float* l      = (const float*)d_in[0];
    const float* g      = (const float*)d_in[1];
    const float* weight = (const float*)d_in[2];
    const float* beta_a = (const float*)d_in[3];
    float* out = (float*)d_out;
    float* ws  = (float*)d_ws;

    dim3 gA(NN * CC), bA(256);
    accum_kernel<0><<<gA, bA, 0, stream>>>(l, g, weight, ws);
    accum_kernel<1><<<gA, bA, 0, stream>>>(l, g, weight, ws);
    accum_kernel<2><<<gA, bA, 0, stream>>>(l, g, weight, ws);
    finalize_kernel<<<dim3(NN), dim3(256), 0, stream>>>(beta_a, out, ws);
}